// Round 4
// baseline (180.439 us; speedup 1.0000x reference)
//
#include <hip/hip_runtime.h>

// CRF forward (log-partition), SEQ=512, BATCH=1024, TAGS=32, fp32 in/out.
//
// R13: algorithm switch. R9-R12 evidence: the matrix-product formulation
// (32x32 chunk matrices, 4 MFMA + ~25 VALU per step per batch) is issue/
// latency-bound at 57-68us regardless of occupancy (R11) or per-wave ILP
// (R12); its MFMA floor alone is ~14us (34 TFLOP). The output is a bilinear
// form w_end^T (Prod_t M_t) e_30, so it splits into TWO VECTOR chains
// meeting in the middle:
//   forward:  alpha <- f_t o (E alpha),   t = 0..255
//   backward: u     <- E^T (f_t o u),     t = 511..256
//   out[b] = ln2*(c2f + c2b + log2(dot(u, alpha)))
// Per step per 16 batches: 2 MFMA 16x16x32 (32x fewer FLOPs than R12) and,
// with B-columns = batches, the D layout (row=4q+p) IS the next B-fragment's
// k-slot set {4q..4q+3, 16+4q..16+4q+3} -> no cross-lane shuffle per step.
// Grid: 64 blocks x 2 waves (fwd+bwd per 16-batch group) - a latency race,
// not an occupancy play. Feats stream through a global_load_lds ring
// (depth 14, counted vmcnt(39), never 0); global sources pre-swizzled so the
// linear LDS dest gives conflict-light ds_read_b128 (2-way max).
// Memory floor: 66 MB / 6.3 TB/s ~ 10.5 us.

constexpr int SEQ = 512, BATCH = 1024, TAGS = 32;
constexpr int HALF = SEQ / 2;     // 256 steps per direction
constexpr int DPF = 14;           // prefetch depth in steps (vmcnt(3*(DPF-1))=39)
constexpr int RING = 16;          // ring slots per wave
constexpr int SLOTF = 512;        // feats dwords per slot (16 b x 32 tags f32)
constexpr int SLOT = SLOTF + 64;  // + 256 B mask replica

#define LOG2E 1.4426950408889634f
#define LN2   0.6931471805599453f

typedef __attribute__((ext_vector_type(8))) short short8;
typedef __attribute__((ext_vector_type(4))) float float4v;
union Frag8 { unsigned u[4]; short8 v; };

__device__ __forceinline__ unsigned pk_rn(float x, float y) {  // bf16 pack, x->low
  return __builtin_amdgcn_perm(__float_as_uint(y) + 0x8000u,
                               __float_as_uint(x) + 0x8000u, 0x07060302u);
}
__device__ __forceinline__ unsigned pk_tr(float x, float y) {  // trunc pack, x->low
  return __builtin_amdgcn_perm(__float_as_uint(y), __float_as_uint(x), 0x07060302u);
}

__device__ __forceinline__ void gld16(const float* g, unsigned* l) {
  __builtin_amdgcn_global_load_lds((const __attribute__((address_space(1))) void*)g,
                                   (__attribute__((address_space(3))) void*)l, 16, 0, 0);
}
__device__ __forceinline__ void gld4(const float* g, unsigned* l) {
  __builtin_amdgcn_global_load_lds((const __attribute__((address_space(1))) void*)g,
                                   (__attribute__((address_space(3))) void*)l, 4, 0, 0);
}

template <bool FWD>
__device__ __forceinline__ void run_chain(
    const float* __restrict__ feats, const float* __restrict__ maskp,
    const float* __restrict__ trans, float* __restrict__ out,
    unsigned* __restrict__ ring, float* __restrict__ vbuf,
    float* __restrict__ c2buf, int b0, int lane) {
  const int s = lane & 15, q = lane >> 4;

  // ---- global sources, pre-swizzled (m173 pattern): LDS dest is linear
  // (lane*16B); we permute WHICH (batch, tag-group) each lane fetches so the
  // later ds_read_b128 at off0/off1 is conflict-light. Block (b, jg) lives at
  // slot dword b*32 + (jg ^ (b&7))*4; load0 covers b 0..7, load1 b 8..15.
  const int bl = lane >> 3;
  const int jg = (lane & 7) ^ (bl & 7);
  const float* src0 = feats + (size_t)(b0 + bl) * TAGS + jg * 4;
  const float* src1 = feats + (size_t)(b0 + 8 + bl) * TAGS + jg * 4;
  const float* srcm = maskp + b0 + s;
  const size_t fstep = (size_t)BATCH * TAGS;

  // LDS read offsets (dwords in slot): lane (s,q) reads feats[gt][b0+s][4q..]
  // and [16+4q..]; start-bank spread = 4*(q^(s&7)) -> linear-equivalent.
  const int off0 = s * 32 + ((q ^ (s & 7)) << 2);
  const int off1 = s * 32 + (((q + 4) ^ (s & 7)) << 2);
  const int offm = SLOTF + s + 16 * q;

  auto ISSUE = [&](int r) {  // stage loads for chain-step r (clamped tail)
    const int rc = (r < HALF) ? r : (HALF - 1);  // dup of last step: same data
    const int gt = FWD ? rc : (SEQ - 1 - rc);
    unsigned* sl = ring + (rc & (RING - 1)) * SLOT;
    gld16(src0 + (size_t)gt * fstep, sl);          // HW dest: sl + lane*16B
    gld16(src1 + (size_t)gt * fstep, sl + 256);
    gld4(srcm + (size_t)gt * BATCH, sl + SLOTF);   // HW dest: +lane*4B
  };

#pragma unroll
  for (int d = 0; d < DPF; ++d) ISSUE(d);

  // ---- constants: sigma-permuted E fragments (A-operand layout: row=l&15,
  // k in sig order {4q..4q+3, 16+4q..16+4q+3} - verified by R9-R12 kernels).
  int sig[8];
#pragma unroll
  for (int i = 0; i < 8; ++i) sig[i] = (i < 4) ? (4 * q + i) : (16 + 4 * q + (i - 4));
  Frag8 e0, e1;  // FWD: E rows (D=E*B). BWD: E^T rows (D=E^T*B).
#pragma unroll
  for (int p = 0; p < 4; ++p) {
    if (FWD) {
      e0.u[p] = pk_rn(__builtin_amdgcn_exp2f(trans[s * TAGS + sig[2 * p]] * LOG2E),
                      __builtin_amdgcn_exp2f(trans[s * TAGS + sig[2 * p + 1]] * LOG2E));
      e1.u[p] = pk_rn(__builtin_amdgcn_exp2f(trans[(16 + s) * TAGS + sig[2 * p]] * LOG2E),
                      __builtin_amdgcn_exp2f(trans[(16 + s) * TAGS + sig[2 * p + 1]] * LOG2E));
    } else {
      e0.u[p] = pk_rn(__builtin_amdgcn_exp2f(trans[sig[2 * p] * TAGS + s] * LOG2E),
                      __builtin_amdgcn_exp2f(trans[sig[2 * p + 1] * TAGS + s] * LOG2E));
      e1.u[p] = pk_rn(__builtin_amdgcn_exp2f(trans[sig[2 * p] * TAGS + 16 + s] * LOG2E),
                      __builtin_amdgcn_exp2f(trans[sig[2 * p + 1] * TAGS + 16 + s] * LOG2E));
    }
  }

  // ---- state: a[i] = vec[j][b=s] with j = (i<4 ? 4q+i : 16+4q+(i-4)).
  float a[8];
#pragma unroll
  for (int i = 0; i < 8; ++i) {
    if (FWD) a[i] = (q == 3 && i == 6) ? 1.0f : 0.0f;  // alpha0 = e_30 (30=16+4*3+2)
    else a[i] = __builtin_amdgcn_exp2f(
        trans[31 * TAGS + ((i < 4) ? (4 * q + i) : (16 + 4 * q + (i - 4)))] * LOG2E);
  }
  Frag8 Bf;  // FWD: packed alpha (B-operand for next step)
  Bf.u[0] = pk_tr(a[0], a[1]); Bf.u[1] = pk_tr(a[2], a[3]);
  Bf.u[2] = pk_tr(a[4], a[5]); Bf.u[3] = pk_tr(a[6], a[7]);
  float c2 = 0.f;
  const float4v zerov = {0.f, 0.f, 0.f, 0.f};

  // ---- F pipeline prologue: slot 0 -> Fc (f' = exp(feat), f32), mc (mask)
  asm volatile("s_waitcnt vmcnt(39)" ::: "memory");
  float4v Fc0, Fc1;
  float mc;
  {
    const unsigned* sl = ring;
    const float4v r0 = *(const float4v*)(const void*)(sl + off0);
    const float4v r1 = *(const float4v*)(const void*)(sl + off1);
    const unsigned mw = sl[offm];
#pragma unroll
    for (int i = 0; i < 4; ++i) {
      Fc0[i] = __builtin_amdgcn_exp2f(r0[i] * LOG2E);
      Fc1[i] = __builtin_amdgcn_exp2f(r1[i] * LOG2E);
    }
    mc = __uint_as_float(mw);
  }

#pragma unroll 2
  for (int r = 0; r < HALF; ++r) {
    ISSUE(r + DPF);
    asm volatile("s_waitcnt vmcnt(39)" ::: "memory");  // slot r+1 complete
    const unsigned* sl = ring + ((r + 1) & (RING - 1)) * SLOT;
    const float4v r0 = *(const float4v*)(const void*)(sl + off0);
    const float4v r1 = *(const float4v*)(const void*)(sl + off1);
    const unsigned mw = sl[offm];

    const bool mv = (mc != 0.0f);
    if (FWD) {
      // alpha' = F o (E alpha):  D rows 4q+p == next B k-slots -> same lane.
      const float4v D0 = __builtin_amdgcn_mfma_f32_16x16x32_bf16(e0.v, Bf.v, zerov, 0, 0, 0);
      const float4v D1 = __builtin_amdgcn_mfma_f32_16x16x32_bf16(e1.v, Bf.v, zerov, 0, 0, 0);
#pragma unroll
      for (int i = 0; i < 4; ++i) {
        a[i]     = mv ? D0[i] * Fc0[i] : a[i];
        a[4 + i] = mv ? D1[i] * Fc1[i] : a[4 + i];
      }
    } else {
      // u' = E^T (F o u): mul before pack/MFMA.
      float tb[8];
#pragma unroll
      for (int i = 0; i < 4; ++i) { tb[i] = a[i] * Fc0[i]; tb[4 + i] = a[4 + i] * Fc1[i]; }
      Frag8 Bp;
      Bp.u[0] = pk_tr(tb[0], tb[1]); Bp.u[1] = pk_tr(tb[2], tb[3]);
      Bp.u[2] = pk_tr(tb[4], tb[5]); Bp.u[3] = pk_tr(tb[6], tb[7]);
      const float4v D0 = __builtin_amdgcn_mfma_f32_16x16x32_bf16(e0.v, Bp.v, zerov, 0, 0, 0);
      const float4v D1 = __builtin_amdgcn_mfma_f32_16x16x32_bf16(e1.v, Bp.v, zerov, 0, 0, 0);
#pragma unroll
      for (int i = 0; i < 4; ++i) {
        a[i]     = mv ? D0[i] : a[i];
        a[4 + i] = mv ? D1[i] : a[4 + i];
      }
    }

    if ((r & 7) == 7) {  // per-column renorm (max over 32 tags of column s)
      float mx = fmaxf(fmaxf(fmaxf(a[0], a[1]), fmaxf(a[2], a[3])),
                       fmaxf(fmaxf(a[4], a[5]), fmaxf(a[6], a[7])));
      mx = fmaxf(mx, __shfl_xor(mx, 16, 64));
      mx = fmaxf(mx, __shfl_xor(mx, 32, 64));
      const int ex = (int)((__float_as_uint(mx) >> 23) & 0xFFu) - 127;
      const float scl = __uint_as_float((unsigned)(127 - ex) << 23);  // exact 2^-ex
#pragma unroll
      for (int i = 0; i < 8; ++i) a[i] *= scl;
      c2 += (float)ex;
    }

    if (FWD) {  // repack alpha for next step's B operand
      Bf.u[0] = pk_tr(a[0], a[1]); Bf.u[1] = pk_tr(a[2], a[3]);
      Bf.u[2] = pk_tr(a[4], a[5]); Bf.u[3] = pk_tr(a[6], a[7]);
    }

    // F pipeline rotate: prep f' for step r+1 (off critical path)
#pragma unroll
    for (int i = 0; i < 4; ++i) {
      Fc0[i] = __builtin_amdgcn_exp2f(r0[i] * LOG2E);
      Fc1[i] = __builtin_amdgcn_exp2f(r1[i] * LOG2E);
    }
    mc = __uint_as_float(mw);
  }

  // ---- junction: out[b] = ln2 * (c2f + c2b + log2(dot(u, alpha)))
  if (!FWD) {
    float4v lo = {a[0], a[1], a[2], a[3]}, hi = {a[4], a[5], a[6], a[7]};
    *(float4v*)(vbuf + lane * 8) = lo;
    *(float4v*)(vbuf + lane * 8 + 4) = hi;
    if (lane < 16) c2buf[lane] = c2;  // c2b per column (q==0 copy)
  }
  __syncthreads();
  if (FWD) {
    const float4v v0 = *(const float4v*)(vbuf + lane * 8);
    const float4v v1 = *(const float4v*)(vbuf + lane * 8 + 4);
    float dot = a[0] * v0[0] + a[1] * v0[1] + a[2] * v0[2] + a[3] * v0[3] +
                a[4] * v1[0] + a[5] * v1[1] + a[6] * v1[2] + a[7] * v1[3];
    dot += __shfl_xor(dot, 16, 64);
    dot += __shfl_xor(dot, 32, 64);  // dot(col s) on all q
    if (lane < 16)
      out[b0 + lane] = LN2 * (c2 + c2buf[lane] + __builtin_amdgcn_logf(dot));
  }
}

extern "C" __global__ void __launch_bounds__(128) crf_scan(
    const float* __restrict__ feats, const float* __restrict__ mask,
    const float* __restrict__ trans, float* __restrict__ out) {
  __shared__ unsigned ring2[2][RING * SLOT];  // 73,728 B (2 waves x 16 slots)
  __shared__ float vbuf[512];
  __shared__ float c2buf[16];
  const int wid = threadIdx.x >> 6;
  const int lane = threadIdx.x & 63;
  const int b0 = blockIdx.x * 16;  // 16 batches per block
  if (wid == 0)
    run_chain<true>(feats, mask, trans, out, &ring2[0][0], vbuf, c2buf, b0, lane);
  else
    run_chain<false>(feats, mask, trans, out, &ring2[1][0], vbuf, c2buf, b0, lane);
}

extern "C" void kernel_launch(void* const* d_in, const int* in_sizes, int n_in,
                              void* d_out, int out_size, void* d_ws, size_t ws_size,
                              hipStream_t stream) {
  const float* feats = (const float*)d_in[0];
  const float* mask  = (const float*)d_in[1];
  const float* trans = (const float*)d_in[2];
  float* out = (float*)d_out;
  hipLaunchKernelGGL(crf_scan, dim3(BATCH / 16), dim3(128), 0, stream,
                     feats, mask, trans, out);
}

// Round 5
// 123.239 us; speedup vs baseline: 1.4641x; 1.4641x over previous
//
#include <hip/hip_runtime.h>

// CRF forward (log-partition), SEQ=512, BATCH=1024, TAGS=32, fp32 in/out.
//
// R14: register-pipeline fix of R13. R13's two-vector-chain algorithm
// (fwd alpha <- f_t o (E alpha), bwd u <- E^T(f_t o u), meet in middle)
// was right, but its global_load_lds ring serialized: the compiler cannot
// prove which pending LDS-write covers which ds_read, so it inserted a
// conservative vmcnt drain per step -> every step paid full memory latency
// (~1300 cy/step measured, 124-147us). R14 removes LDS from the main loop
// entirely: feats/mask stream through a depth-8 ROTATING REGISTER buffer
// (statically indexed via full unroll), so the compiler tracks each load
// per-register and emits precise counted vmcnt(N) before each use. Slot j
// is loaded ~7 step-bodies (~800 cy) before consumption - covers warm-L3
// latency (inputs are L3-resident across dispatches: FETCH 35MB < 64MB
// ideal). exp(feat) is prepared one step ahead (off the MFMA critical
// path). LDS = 2KB junction buffer only.
// Grid: 64 blocks x 2 waves (fwd+bwd per 16-batch group) - latency race.

constexpr int SEQ = 512, BATCH = 1024, TAGS = 32;
constexpr int HALF = SEQ / 2;  // 256 steps per direction
constexpr int D = 8;           // register pipeline depth (steps)

#define LOG2E 1.4426950408889634f
#define LN2   0.6931471805599453f

typedef __attribute__((ext_vector_type(8))) short short8;
typedef __attribute__((ext_vector_type(4))) float float4v;
union Frag8 { unsigned u[4]; short8 v; };

__device__ __forceinline__ unsigned pk_rn(float x, float y) {  // bf16 pack, x->low
  return __builtin_amdgcn_perm(__float_as_uint(y) + 0x8000u,
                               __float_as_uint(x) + 0x8000u, 0x07060302u);
}
__device__ __forceinline__ unsigned pk_tr(float x, float y) {  // trunc pack, x->low
  return __builtin_amdgcn_perm(__float_as_uint(y), __float_as_uint(x), 0x07060302u);
}

template <bool FWD>
__device__ __forceinline__ void run_chain(
    const float* __restrict__ feats, const float* __restrict__ maskp,
    const float* __restrict__ trans, float* __restrict__ out,
    float* __restrict__ vbuf, float* __restrict__ c2buf, int b0, int lane) {
  const int s = lane & 15, q = lane >> 4;

  // per-lane stream bases: lane (s,q) reads feats[t][b0+s][4q..4q+3] and
  // [16+4q..16+4q+3] (16B aligned), mask[t][b0+s]. t walks fwd or bwd.
  const size_t fstep = (size_t)BATCH * TAGS;
  const ptrdiff_t fs = FWD ? (ptrdiff_t)fstep : -(ptrdiff_t)fstep;
  const ptrdiff_t ms = FWD ? (ptrdiff_t)BATCH : -(ptrdiff_t)BATCH;
  const float* pLo = feats + (size_t)(b0 + s) * TAGS + 4 * q +
                     (FWD ? 0 : (size_t)(SEQ - 1) * fstep);
  const float* pHi = pLo + 16;
  const float* pM = maskp + b0 + s + (FWD ? 0 : (size_t)(SEQ - 1) * BATCH);

  // ---- register pipeline: slot j holds raw feats/mask for step r, j = r&7
  float4v Rlo[D], Rhi[D];
  float Rm[D];
#pragma unroll
  for (int d = 0; d < D; ++d) {
    Rlo[d] = *(const float4v*)(pLo + (ptrdiff_t)d * fs);
    Rhi[d] = *(const float4v*)(pHi + (ptrdiff_t)d * fs);
    Rm[d] = *(pM + (ptrdiff_t)d * ms);
  }

  // ---- constants: sigma-permuted E fragments (A-operand layout: row=l&15,
  // k in sig order {4q..4q+3, 16+4q..16+4q+3} - verified by R9-R13 kernels).
  int sig[8];
#pragma unroll
  for (int i = 0; i < 8; ++i) sig[i] = (i < 4) ? (4 * q + i) : (16 + 4 * q + (i - 4));
  Frag8 e0, e1;  // FWD: E rows (D=E*B). BWD: E^T rows (D=E^T*B).
#pragma unroll
  for (int p = 0; p < 4; ++p) {
    if (FWD) {
      e0.u[p] = pk_rn(__builtin_amdgcn_exp2f(trans[s * TAGS + sig[2 * p]] * LOG2E),
                      __builtin_amdgcn_exp2f(trans[s * TAGS + sig[2 * p + 1]] * LOG2E));
      e1.u[p] = pk_rn(__builtin_amdgcn_exp2f(trans[(16 + s) * TAGS + sig[2 * p]] * LOG2E),
                      __builtin_amdgcn_exp2f(trans[(16 + s) * TAGS + sig[2 * p + 1]] * LOG2E));
    } else {
      e0.u[p] = pk_rn(__builtin_amdgcn_exp2f(trans[sig[2 * p] * TAGS + s] * LOG2E),
                      __builtin_amdgcn_exp2f(trans[sig[2 * p + 1] * TAGS + s] * LOG2E));
      e1.u[p] = pk_rn(__builtin_amdgcn_exp2f(trans[sig[2 * p] * TAGS + 16 + s] * LOG2E),
                      __builtin_amdgcn_exp2f(trans[sig[2 * p + 1] * TAGS + 16 + s] * LOG2E));
    }
  }

  // ---- state: a[i] = vec[j][b=s] with j = (i<4 ? 4q+i : 16+4q+(i-4)).
  float a[8];
#pragma unroll
  for (int i = 0; i < 8; ++i) {
    if (FWD) a[i] = (q == 3 && i == 6) ? 1.0f : 0.0f;  // alpha0 = e_30 (30=16+4*3+2)
    else a[i] = __builtin_amdgcn_exp2f(
        trans[31 * TAGS + ((i < 4) ? (4 * q + i) : (16 + 4 * q + (i - 4)))] * LOG2E);
  }
  Frag8 Bf;  // FWD: packed alpha (B-operand for next step)
  Bf.u[0] = pk_tr(a[0], a[1]); Bf.u[1] = pk_tr(a[2], a[3]);
  Bf.u[2] = pk_tr(a[4], a[5]); Bf.u[3] = pk_tr(a[6], a[7]);
  float c2 = 0.f;
  const float4v zerov = {0.f, 0.f, 0.f, 0.f};

  // ---- Fc pipeline prologue: exp of slot 0 (step 0)
  float4v Fc0, Fc1;
  float mc;
#pragma unroll
  for (int i = 0; i < 4; ++i) {
    Fc0[i] = __builtin_amdgcn_exp2f(Rlo[0][i] * LOG2E);
    Fc1[i] = __builtin_amdgcn_exp2f(Rhi[0][i] * LOG2E);
  }
  mc = Rm[0];

  for (int r8 = 0; r8 < HALF / D; ++r8) {
    const bool issue = (r8 < HALF / D - 1);
    const float* qLo = pLo + (ptrdiff_t)(r8 + 1) * D * fs;
    const float* qHi = qLo + 16;
    const float* qM = pM + (ptrdiff_t)(r8 + 1) * D * ms;
#pragma unroll
    for (int u = 0; u < D; ++u) {
      // prefetch step r8*8+8+u into slot u (consumed ~7 bodies later)
      if (issue) {
        Rlo[u] = *(const float4v*)(qLo + (ptrdiff_t)u * fs);
        Rhi[u] = *(const float4v*)(qHi + (ptrdiff_t)u * fs);
        Rm[u] = *(qM + (ptrdiff_t)u * ms);
      }

      const bool mv = (mc != 0.0f);
      if (FWD) {
        // alpha' = F o (E alpha): D rows 4q+p == next B k-slots -> same lane.
        const float4v D0 = __builtin_amdgcn_mfma_f32_16x16x32_bf16(e0.v, Bf.v, zerov, 0, 0, 0);
        const float4v D1 = __builtin_amdgcn_mfma_f32_16x16x32_bf16(e1.v, Bf.v, zerov, 0, 0, 0);
#pragma unroll
        for (int i = 0; i < 4; ++i) {
          a[i] = mv ? D0[i] * Fc0[i] : a[i];
          a[4 + i] = mv ? D1[i] * Fc1[i] : a[4 + i];
        }
      } else {
        // u' = E^T (F o u): mul before pack/MFMA.
        float tb[8];
#pragma unroll
        for (int i = 0; i < 4; ++i) { tb[i] = a[i] * Fc0[i]; tb[4 + i] = a[4 + i] * Fc1[i]; }
        Frag8 Bp;
        Bp.u[0] = pk_tr(tb[0], tb[1]); Bp.u[1] = pk_tr(tb[2], tb[3]);
        Bp.u[2] = pk_tr(tb[4], tb[5]); Bp.u[3] = pk_tr(tb[6], tb[7]);
        const float4v D0 = __builtin_amdgcn_mfma_f32_16x16x32_bf16(e0.v, Bp.v, zerov, 0, 0, 0);
        const float4v D1 = __builtin_amdgcn_mfma_f32_16x16x32_bf16(e1.v, Bp.v, zerov, 0, 0, 0);
#pragma unroll
        for (int i = 0; i < 4; ++i) {
          a[i] = mv ? D0[i] : a[i];
          a[4 + i] = mv ? D1[i] : a[4 + i];
        }
      }

      if (u == 7) {  // renorm every 8 steps (per-column max over 32 tags)
        float mx = fmaxf(fmaxf(fmaxf(a[0], a[1]), fmaxf(a[2], a[3])),
                         fmaxf(fmaxf(a[4], a[5]), fmaxf(a[6], a[7])));
        mx = fmaxf(mx, __shfl_xor(mx, 16, 64));
        mx = fmaxf(mx, __shfl_xor(mx, 32, 64));
        const int ex = (int)((__float_as_uint(mx) >> 23) & 0xFFu) - 127;
        const float scl = __uint_as_float((unsigned)(127 - ex) << 23);  // exact 2^-ex
#pragma unroll
        for (int i = 0; i < 8; ++i) a[i] *= scl;
        c2 += (float)ex;
      }

      if (FWD) {  // repack alpha for next step's B operand
        Bf.u[0] = pk_tr(a[0], a[1]); Bf.u[1] = pk_tr(a[2], a[3]);
        Bf.u[2] = pk_tr(a[4], a[5]); Bf.u[3] = pk_tr(a[6], a[7]);
      }

      // Fc rotate: prep exp for step r+1 from slot (u+1)&7 (written 7 bodies
      // ago; overwritten only at the TOP of body u+1 -> in-order safe).
      const int nu = (u + 1) & 7;
#pragma unroll
      for (int i = 0; i < 4; ++i) {
        Fc0[i] = __builtin_amdgcn_exp2f(Rlo[nu][i] * LOG2E);
        Fc1[i] = __builtin_amdgcn_exp2f(Rhi[nu][i] * LOG2E);
      }
      mc = Rm[nu];
    }
  }

  // ---- junction: out[b] = ln2 * (c2f + c2b + log2(dot(u, alpha)))
  if (!FWD) {
    float4v lo = {a[0], a[1], a[2], a[3]}, hi = {a[4], a[5], a[6], a[7]};
    *(float4v*)(vbuf + lane * 8) = lo;
    *(float4v*)(vbuf + lane * 8 + 4) = hi;
    if (lane < 16) c2buf[lane] = c2;  // c2b per column
  }
  __syncthreads();
  if (FWD) {
    const float4v v0 = *(const float4v*)(vbuf + lane * 8);
    const float4v v1 = *(const float4v*)(vbuf + lane * 8 + 4);
    float dot = a[0] * v0[0] + a[1] * v0[1] + a[2] * v0[2] + a[3] * v0[3] +
                a[4] * v1[0] + a[5] * v1[1] + a[6] * v1[2] + a[7] * v1[3];
    dot += __shfl_xor(dot, 16, 64);
    dot += __shfl_xor(dot, 32, 64);  // dot(col s) on all q
    if (lane < 16)
      out[b0 + lane] = LN2 * (c2 + c2buf[lane] + __builtin_amdgcn_logf(dot));
  }
}

extern "C" __global__ void __launch_bounds__(128) crf_scan(
    const float* __restrict__ feats, const float* __restrict__ mask,
    const float* __restrict__ trans, float* __restrict__ out) {
  __shared__ float vbuf[512];
  __shared__ float c2buf[16];
  const int wid = threadIdx.x >> 6;
  const int lane = threadIdx.x & 63;
  const int b0 = blockIdx.x * 16;  // 16 batches per block
  if (wid == 0)
    run_chain<true>(feats, mask, trans, out, vbuf, c2buf, b0, lane);
  else
    run_chain<false>(feats, mask, trans, out, vbuf, c2buf, b0, lane);
}

extern "C" void kernel_launch(void* const* d_in, const int* in_sizes, int n_in,
                              void* d_out, int out_size, void* d_ws, size_t ws_size,
                              hipStream_t stream) {
  const float* feats = (const float*)d_in[0];
  const float* mask  = (const float*)d_in[1];
  const float* trans = (const float*)d_in[2];
  float* out = (float*)d_out;
  hipLaunchKernelGGL(crf_scan, dim3(BATCH / 16), dim3(128), 0, stream,
                     feats, mask, trans, out);
}

// Round 6
// 120.590 us; speedup vs baseline: 1.4963x; 1.0220x over previous
//
#include <hip/hip_runtime.h>

// CRF forward (log-partition), SEQ=512, BATCH=1024, TAGS=32, fp32 in/out.
//
// R15: unstrangle R14's register pipeline. R14 (two-vector-chain algorithm,
// depth-8 register prefetch) improved 124->58us but VGPR_Count=64 proved the
// allocator could not hold the pipeline (needs 72+ regs for slots alone):
// loads were sunk to just-before-use, exposing ~545 cy warm-L3 latency per
// step (VALUBusy 5%). R15:
//  1. __launch_bounds__(128, 1): 1 wave/EU -> VGPR budget up to 512; the
//     depth-16 pipeline (~144 regs) + state (~50) fits without spills.
//  2. Pipeline depth 16 (16 bodies/group, fully unrolled): slot u written at
//     body u of group g, consumed at end of body u-1 of group g+1 -> ~15
//     step-bodies (~900+ cy) of latency coverage.
// Algorithm (validated R13/R14): fwd alpha <- f_t o (E alpha) t=0..255;
// bwd u <- E^T (f_t o u) t=511..256; out = ln2*(c2f+c2b+log2(dot(u,alpha))).
// 2 MFMA 16x16x32 per step per 16 batches; D-fragment rows (4q+p) == next
// B-fragment k-slots -> zero cross-lane traffic per step.
// Grid: 64 blocks x 2 waves - a latency race (0.5 waves/CU by design).

constexpr int SEQ = 512, BATCH = 1024, TAGS = 32;
constexpr int HALF = SEQ / 2;  // 256 steps per direction
constexpr int D = 16;          // register pipeline depth (steps)

#define LOG2E 1.4426950408889634f
#define LN2   0.6931471805599453f

typedef __attribute__((ext_vector_type(8))) short short8;
typedef __attribute__((ext_vector_type(4))) float float4v;
union Frag8 { unsigned u[4]; short8 v; };

__device__ __forceinline__ unsigned pk_rn(float x, float y) {  // bf16 pack, x->low
  return __builtin_amdgcn_perm(__float_as_uint(y) + 0x8000u,
                               __float_as_uint(x) + 0x8000u, 0x07060302u);
}
__device__ __forceinline__ unsigned pk_tr(float x, float y) {  // trunc pack, x->low
  return __builtin_amdgcn_perm(__float_as_uint(y), __float_as_uint(x), 0x07060302u);
}

template <bool FWD>
__device__ __forceinline__ void run_chain(
    const float* __restrict__ feats, const float* __restrict__ maskp,
    const float* __restrict__ trans, float* __restrict__ out,
    float* __restrict__ vbuf, float* __restrict__ c2buf, int b0, int lane) {
  const int s = lane & 15, q = lane >> 4;

  // per-lane stream bases: lane (s,q) reads feats[t][b0+s][4q..4q+3] and
  // [16+4q..16+4q+3] (16B aligned), mask[t][b0+s]. t walks fwd or bwd.
  const size_t fstep = (size_t)BATCH * TAGS;
  const ptrdiff_t fs = FWD ? (ptrdiff_t)fstep : -(ptrdiff_t)fstep;
  const ptrdiff_t ms = FWD ? (ptrdiff_t)BATCH : -(ptrdiff_t)BATCH;
  const float* pLo = feats + (size_t)(b0 + s) * TAGS + 4 * q +
                     (FWD ? 0 : (size_t)(SEQ - 1) * fstep);
  const float* pHi = pLo + 16;
  const float* pM = maskp + b0 + s + (FWD ? 0 : (size_t)(SEQ - 1) * BATCH);

  // ---- register pipeline: slot j holds raw feats/mask for step r, j = r&15
  float4v Rlo[D], Rhi[D];
  float Rm[D];
#pragma unroll
  for (int d = 0; d < D; ++d) {
    Rlo[d] = *(const float4v*)(pLo + (ptrdiff_t)d * fs);
    Rhi[d] = *(const float4v*)(pHi + (ptrdiff_t)d * fs);
    Rm[d] = *(pM + (ptrdiff_t)d * ms);
  }

  // ---- constants: sigma-permuted E fragments (A-operand layout: row=l&15,
  // k in sig order {4q..4q+3, 16+4q..16+4q+3} - verified by R9-R14 kernels).
  int sig[8];
#pragma unroll
  for (int i = 0; i < 8; ++i) sig[i] = (i < 4) ? (4 * q + i) : (16 + 4 * q + (i - 4));
  Frag8 e0, e1;  // FWD: E rows (D=E*B). BWD: E^T rows (D=E^T*B).
#pragma unroll
  for (int p = 0; p < 4; ++p) {
    if (FWD) {
      e0.u[p] = pk_rn(__builtin_amdgcn_exp2f(trans[s * TAGS + sig[2 * p]] * LOG2E),
                      __builtin_amdgcn_exp2f(trans[s * TAGS + sig[2 * p + 1]] * LOG2E));
      e1.u[p] = pk_rn(__builtin_amdgcn_exp2f(trans[(16 + s) * TAGS + sig[2 * p]] * LOG2E),
                      __builtin_amdgcn_exp2f(trans[(16 + s) * TAGS + sig[2 * p + 1]] * LOG2E));
    } else {
      e0.u[p] = pk_rn(__builtin_amdgcn_exp2f(trans[sig[2 * p] * TAGS + s] * LOG2E),
                      __builtin_amdgcn_exp2f(trans[sig[2 * p + 1] * TAGS + s] * LOG2E));
      e1.u[p] = pk_rn(__builtin_amdgcn_exp2f(trans[sig[2 * p] * TAGS + 16 + s] * LOG2E),
                      __builtin_amdgcn_exp2f(trans[sig[2 * p + 1] * TAGS + 16 + s] * LOG2E));
    }
  }

  // ---- state: a[i] = vec[j][b=s] with j = (i<4 ? 4q+i : 16+4q+(i-4)).
  float a[8];
#pragma unroll
  for (int i = 0; i < 8; ++i) {
    if (FWD) a[i] = (q == 3 && i == 6) ? 1.0f : 0.0f;  // alpha0 = e_30 (30=16+4*3+2)
    else a[i] = __builtin_amdgcn_exp2f(
        trans[31 * TAGS + ((i < 4) ? (4 * q + i) : (16 + 4 * q + (i - 4)))] * LOG2E);
  }
  Frag8 Bf;  // FWD: packed alpha (B-operand for next step)
  Bf.u[0] = pk_tr(a[0], a[1]); Bf.u[1] = pk_tr(a[2], a[3]);
  Bf.u[2] = pk_tr(a[4], a[5]); Bf.u[3] = pk_tr(a[6], a[7]);
  float c2 = 0.f;
  const float4v zerov = {0.f, 0.f, 0.f, 0.f};

  // ---- Fc pipeline prologue: exp of slot 0 (step 0)
  float4v Fc0, Fc1;
  float mc;
#pragma unroll
  for (int i = 0; i < 4; ++i) {
    Fc0[i] = __builtin_amdgcn_exp2f(Rlo[0][i] * LOG2E);
    Fc1[i] = __builtin_amdgcn_exp2f(Rhi[0][i] * LOG2E);
  }
  mc = Rm[0];

  for (int g = 0; g < HALF / D; ++g) {
    const bool issue = (g < HALF / D - 1);
    const float* qLo = pLo + (ptrdiff_t)(g + 1) * D * fs;
    const float* qHi = qLo + 16;
    const float* qM = pM + (ptrdiff_t)(g + 1) * D * ms;
#pragma unroll
    for (int u = 0; u < D; ++u) {
      // prefetch step g*16+16+u into slot u (consumed ~15 bodies later)
      if (issue) {
        Rlo[u] = *(const float4v*)(qLo + (ptrdiff_t)u * fs);
        Rhi[u] = *(const float4v*)(qHi + (ptrdiff_t)u * fs);
        Rm[u] = *(qM + (ptrdiff_t)u * ms);
      }

      const bool mv = (mc != 0.0f);
      if (FWD) {
        // alpha' = F o (E alpha): D rows 4q+p == next B k-slots -> same lane.
        const float4v D0 = __builtin_amdgcn_mfma_f32_16x16x32_bf16(e0.v, Bf.v, zerov, 0, 0, 0);
        const float4v D1 = __builtin_amdgcn_mfma_f32_16x16x32_bf16(e1.v, Bf.v, zerov, 0, 0, 0);
#pragma unroll
        for (int i = 0; i < 4; ++i) {
          a[i] = mv ? D0[i] * Fc0[i] : a[i];
          a[4 + i] = mv ? D1[i] * Fc1[i] : a[4 + i];
        }
      } else {
        // u' = E^T (F o u): mul before pack/MFMA.
        float tb[8];
#pragma unroll
        for (int i = 0; i < 4; ++i) { tb[i] = a[i] * Fc0[i]; tb[4 + i] = a[4 + i] * Fc1[i]; }
        Frag8 Bp;
        Bp.u[0] = pk_tr(tb[0], tb[1]); Bp.u[1] = pk_tr(tb[2], tb[3]);
        Bp.u[2] = pk_tr(tb[4], tb[5]); Bp.u[3] = pk_tr(tb[6], tb[7]);
        const float4v D0 = __builtin_amdgcn_mfma_f32_16x16x32_bf16(e0.v, Bp.v, zerov, 0, 0, 0);
        const float4v D1 = __builtin_amdgcn_mfma_f32_16x16x32_bf16(e1.v, Bp.v, zerov, 0, 0, 0);
#pragma unroll
        for (int i = 0; i < 4; ++i) {
          a[i] = mv ? D0[i] : a[i];
          a[4 + i] = mv ? D1[i] : a[4 + i];
        }
      }

      if ((u & 7) == 7) {  // renorm every 8 steps (per-column max over 32 tags)
        float mx = fmaxf(fmaxf(fmaxf(a[0], a[1]), fmaxf(a[2], a[3])),
                         fmaxf(fmaxf(a[4], a[5]), fmaxf(a[6], a[7])));
        mx = fmaxf(mx, __shfl_xor(mx, 16, 64));
        mx = fmaxf(mx, __shfl_xor(mx, 32, 64));
        const int ex = (int)((__float_as_uint(mx) >> 23) & 0xFFu) - 127;
        const float scl = __uint_as_float((unsigned)(127 - ex) << 23);  // exact 2^-ex
#pragma unroll
        for (int i = 0; i < 8; ++i) a[i] *= scl;
        c2 += (float)ex;
      }

      if (FWD) {  // repack alpha for next step's B operand
        Bf.u[0] = pk_tr(a[0], a[1]); Bf.u[1] = pk_tr(a[2], a[3]);
        Bf.u[2] = pk_tr(a[4], a[5]); Bf.u[3] = pk_tr(a[6], a[7]);
      }

      // Fc rotate: prep exp for the next step from slot (u+1)&15 (written
      // ~15 bodies ago; overwritten only at the TOP of body u+1 -> safe).
      const int nu = (u + 1) & (D - 1);
#pragma unroll
      for (int i = 0; i < 4; ++i) {
        Fc0[i] = __builtin_amdgcn_exp2f(Rlo[nu][i] * LOG2E);
        Fc1[i] = __builtin_amdgcn_exp2f(Rhi[nu][i] * LOG2E);
      }
      mc = Rm[nu];
    }
  }

  // ---- junction: out[b] = ln2 * (c2f + c2b + log2(dot(u, alpha)))
  if (!FWD) {
    float4v lo = {a[0], a[1], a[2], a[3]}, hi = {a[4], a[5], a[6], a[7]};
    *(float4v*)(vbuf + lane * 8) = lo;
    *(float4v*)(vbuf + lane * 8 + 4) = hi;
    if (lane < 16) c2buf[lane] = c2;  // c2b per column
  }
  __syncthreads();
  if (FWD) {
    const float4v v0 = *(const float4v*)(vbuf + lane * 8);
    const float4v v1 = *(const float4v*)(vbuf + lane * 8 + 4);
    float dot = a[0] * v0[0] + a[1] * v0[1] + a[2] * v0[2] + a[3] * v0[3] +
                a[4] * v1[0] + a[5] * v1[1] + a[6] * v1[2] + a[7] * v1[3];
    dot += __shfl_xor(dot, 16, 64);
    dot += __shfl_xor(dot, 32, 64);  // dot(col s) on all q
    if (lane < 16)
      out[b0 + lane] = LN2 * (c2 + c2buf[lane] + __builtin_amdgcn_logf(dot));
  }
}

extern "C" __global__ void __launch_bounds__(128, 1) crf_scan(
    const float* __restrict__ feats, const float* __restrict__ mask,
    const float* __restrict__ trans, float* __restrict__ out) {
  __shared__ float vbuf[512];
  __shared__ float c2buf[16];
  const int wid = threadIdx.x >> 6;
  const int lane = threadIdx.x & 63;
  const int b0 = blockIdx.x * 16;  // 16 batches per block
  if (wid == 0)
    run_chain<true>(feats, mask, trans, out, vbuf, c2buf, b0, lane);
  else
    run_chain<false>(feats, mask, trans, out, vbuf, c2buf, b0, lane);
}

extern "C" void kernel_launch(void* const* d_in, const int* in_sizes, int n_in,
                              void* d_out, int out_size, void* d_ws, size_t ws_size,
                              hipStream_t stream) {
  const float* feats = (const float*)d_in[0];
  const float* mask  = (const float*)d_in[1];
  const float* trans = (const float*)d_in[2];
  float* out = (float*)d_out;
  hipLaunchKernelGGL(crf_scan, dim3(BATCH / 16), dim3(128), 0, stream,
                     feats, mask, trans, out);
}

// Round 8
// 117.377 us; speedup vs baseline: 1.5373x; 1.0274x over previous
//
#include <hip/hip_runtime.h>

// CRF forward (log-partition), SEQ=512, BATCH=1024, TAGS=32, fp32 in/out.
//
// R17: producer/consumer wave split. Evidence trail: R13 (same-wave
// global_load_lds ring) -> compiler drains vmcnt(0) per step (ds_read vs
// pending LDS-write aliasing). R14/R15 (register pipeline) -> pre-RA
// scheduler sinks loads, VGPR_Count 64/104 proves pipeline never held.
// R16 (full inline-asm loads) -> GPU abort (asm in-flight dests + RA
// interaction). Conclusion: same-wave deep prefetch is unreachable at HIP
// source level. Fix: split roles across waves (the m201-proven structure):
//   wave0 = fwd consumer, wave1 = bwd consumer, wave2/3 = producers.
// Producers stream 8-step chunks of feats+mask into double-buffered LDS
// via global_load_lds; __syncthreads() per chunk is the handshake.
// Consumers have NO vmem ops -> their ds_reads carry no vmcnt hazard (the
// R13 killer is structurally gone); producers have no ds_reads -> their
// auto vmcnt(0)-before-barrier is the intended handshake, amortized over
// 8 steps. Bank conflicts: gld_lds writes linearly, so the GLOBAL source
// is pre-swizzled (m173): lane l fetches tags 4*((l&7)^((l>>3)&7)) of
// batch (l>>3); consumers read with the matching XOR (<=2 addrs/bank grp).
// Algorithm (validated R13-R15): fwd alpha <- f_t o (E alpha) t=0..255;
// bwd u <- E^T (f_t o u) t=511..256; out = ln2*(c2f+c2b+log2(dot(u,alpha))).
// LDS 68 KB (R9 proved 76 KB static OK). Grid 64 blocks x 4 waves.

constexpr int SEQ = 512, BATCH = 1024, TAGS = 32;
constexpr int CH = 8;              // steps per chunk
constexpr int NCH = (SEQ / 2) / CH;  // 32 chunks per direction
constexpr int FSLOT = CH * 512;    // feats dwords per chunk (8 steps x 16b x 32t)
constexpr int MSLOT = CH * 16;     // mask dwords per chunk

#define LOG2E 1.4426950408889634f
#define LN2   0.6931471805599453f

typedef __attribute__((ext_vector_type(8))) short short8;
typedef __attribute__((ext_vector_type(4))) float float4v;
union Frag8 { unsigned u[4]; short8 v; };

__device__ __forceinline__ unsigned pk_rn(float x, float y) {  // bf16 pack, x->low
  return __builtin_amdgcn_perm(__float_as_uint(y) + 0x8000u,
                               __float_as_uint(x) + 0x8000u, 0x07060302u);
}
__device__ __forceinline__ unsigned pk_tr(float x, float y) {  // trunc pack, x->low
  return __builtin_amdgcn_perm(__float_as_uint(y), __float_as_uint(x), 0x07060302u);
}

__device__ __forceinline__ void gld16(const float* g, float* l) {
  __builtin_amdgcn_global_load_lds((const __attribute__((address_space(1))) void*)g,
                                   (__attribute__((address_space(3))) void*)l, 16, 0, 0);
}
__device__ __forceinline__ void gld4(const float* g, float* l) {
  __builtin_amdgcn_global_load_lds((const __attribute__((address_space(1))) void*)g,
                                   (__attribute__((address_space(3))) void*)l, 4, 0, 0);
}

// ---------------- producer: stream chunks into LDS ----------------
template <bool FWD>
__device__ __forceinline__ void produce(
    const float* __restrict__ feats, const float* __restrict__ maskp,
    float* __restrict__ FFd, float* __restrict__ MMd, int b0, int lane) {
  // feats: per step 2 gld16 (batches 0-7, 8-15). LDS dword d of a step slot
  // holds feats[t][b0 + (d>>5)][(d&31) ^ (((d>>5)&7)<<2)] (pre-swizzled src).
  const int bs = lane >> 3;
  const int tg = 4 * ((lane & 7) ^ (bs & 7));
  const size_t t0 = FWD ? 0 : (size_t)(SEQ - 1);
  const float* gF0 = feats + t0 * BATCH * TAGS + (size_t)(b0 + bs) * TAGS + tg;
  const float* gF8 = gF0 + 8 * TAGS;
  // mask: 2 gld4 per chunk; instr covers 4 steps x 16 batches (lane l ->
  // step l>>4, batch l&15).
  const float* gM0 = maskp +
      (FWD ? (size_t)(lane >> 4) : (size_t)(SEQ - 1 - (lane >> 4))) * BATCH +
      b0 + (lane & 15);
  const ptrdiff_t fstep = FWD ? (ptrdiff_t)(BATCH * TAGS) : -(ptrdiff_t)(BATCH * TAGS);
  const ptrdiff_t mstep = FWD ? (ptrdiff_t)BATCH : -(ptrdiff_t)BATCH;

  auto FILL = [&](int k) {
    float* fb = FFd + (k & 1) * FSLOT;
    float* mb = MMd + (k & 1) * MSLOT;
#pragma unroll
    for (int j = 0; j < CH; ++j) {
      const ptrdiff_t o = (ptrdiff_t)(CH * k + j) * fstep;
      gld16(gF0 + o, fb + j * 512);
      gld16(gF8 + o, fb + j * 512 + 256);
    }
    gld4(gM0 + (ptrdiff_t)(CH * k) * mstep, mb);
    gld4(gM0 + (ptrdiff_t)(CH * k + 4) * mstep, mb + 64);
  };

  FILL(0);
  __syncthreads();  // B0: chunk 0 ready
  for (int k = 0; k < NCH; ++k) {
    if (k < NCH - 1) FILL(k + 1);  // fill other buffer while consumers read k
    __syncthreads();               // implicit vmcnt(0) drains this wave's fills
  }
  __syncthreads();  // junction barrier (match consumers)
}

// ---------------- consumer: run one direction's chain ----------------
template <bool FWD>
__device__ __forceinline__ void consume(
    const float* __restrict__ trans, float* __restrict__ out,
    const float* __restrict__ FFd, const float* __restrict__ MMd,
    float* __restrict__ vbuf, float* __restrict__ c2buf, int b0, int lane) {
  const int s = lane & 15, q = lane >> 4;

  // sigma-permuted E fragments (A-operand layout: row=l&15, k in sig order
  // {4q..4q+3, 16+4q..16+4q+3} - verified R9-R15).
  int sig[8];
#pragma unroll
  for (int i = 0; i < 8; ++i) sig[i] = (i < 4) ? (4 * q + i) : (16 + 4 * q + (i - 4));
  Frag8 e0, e1;  // FWD: E rows (D=E*B). BWD: E^T rows.
#pragma unroll
  for (int p = 0; p < 4; ++p) {
    if (FWD) {
      e0.u[p] = pk_rn(__builtin_amdgcn_exp2f(trans[s * TAGS + sig[2 * p]] * LOG2E),
                      __builtin_amdgcn_exp2f(trans[s * TAGS + sig[2 * p + 1]] * LOG2E));
      e1.u[p] = pk_rn(__builtin_amdgcn_exp2f(trans[(16 + s) * TAGS + sig[2 * p]] * LOG2E),
                      __builtin_amdgcn_exp2f(trans[(16 + s) * TAGS + sig[2 * p + 1]] * LOG2E));
    } else {
      e0.u[p] = pk_rn(__builtin_amdgcn_exp2f(trans[sig[2 * p] * TAGS + s] * LOG2E),
                      __builtin_amdgcn_exp2f(trans[sig[2 * p + 1] * TAGS + s] * LOG2E));
      e1.u[p] = pk_rn(__builtin_amdgcn_exp2f(trans[sig[2 * p] * TAGS + 16 + s] * LOG2E),
                      __builtin_amdgcn_exp2f(trans[sig[2 * p + 1] * TAGS + 16 + s] * LOG2E));
    }
  }

  // state: a[i] = vec[j][b=s], j = sig-mapped.
  float a[8];
#pragma unroll
  for (int i = 0; i < 8; ++i) {
    if (FWD) a[i] = (q == 3 && i == 6) ? 1.0f : 0.0f;  // alpha0 = e_30
    else a[i] = __builtin_amdgcn_exp2f(
        trans[31 * TAGS + ((i < 4) ? (4 * q + i) : (16 + 4 * q + (i - 4)))] * LOG2E);
  }
  Frag8 Bf;
  Bf.u[0] = pk_tr(a[0], a[1]); Bf.u[1] = pk_tr(a[2], a[3]);
  Bf.u[2] = pk_tr(a[4], a[5]); Bf.u[3] = pk_tr(a[6], a[7]);
  float c2 = 0.f;
  const float4v zerov = {0.f, 0.f, 0.f, 0.f};

  // consumer LDS read offsets (dwords within a step slot):
  const int off0 = s * 32 + ((q ^ (s & 7)) << 2);
  const int off1 = s * 32 + (((q + 4) ^ (s & 7)) << 2);

  __syncthreads();  // B0: chunk 0 ready
  for (int k = 0; k < NCH; ++k) {
    const float* fb = FFd + (k & 1) * FSLOT;
    const float* mb = MMd + (k & 1) * MSLOT;
#pragma unroll
    for (int j = 0; j < CH; ++j) {
      const float4v r0 = *(const float4v*)(fb + j * 512 + off0);
      const float4v r1 = *(const float4v*)(fb + j * 512 + off1);
      const float mval = mb[j * 16 + s];
      float4v Fc0, Fc1;
#pragma unroll
      for (int i = 0; i < 4; ++i) {
        Fc0[i] = __builtin_amdgcn_exp2f(r0[i] * LOG2E);
        Fc1[i] = __builtin_amdgcn_exp2f(r1[i] * LOG2E);
      }
      const bool mv = (mval != 0.0f);
      if (FWD) {
        // alpha' = F o (E alpha): D rows 4q+p == next B k-slots, same lane.
        const float4v D0 = __builtin_amdgcn_mfma_f32_16x16x32_bf16(e0.v, Bf.v, zerov, 0, 0, 0);
        const float4v D1 = __builtin_amdgcn_mfma_f32_16x16x32_bf16(e1.v, Bf.v, zerov, 0, 0, 0);
#pragma unroll
        for (int i = 0; i < 4; ++i) {
          a[i] = mv ? D0[i] * Fc0[i] : a[i];
          a[4 + i] = mv ? D1[i] * Fc1[i] : a[4 + i];
        }
      } else {
        // u' = E^T (F o u): mul before pack/MFMA.
        float tb[8];
#pragma unroll
        for (int i = 0; i < 4; ++i) { tb[i] = a[i] * Fc0[i]; tb[4 + i] = a[4 + i] * Fc1[i]; }
        Frag8 Bp;
        Bp.u[0] = pk_tr(tb[0], tb[1]); Bp.u[1] = pk_tr(tb[2], tb[3]);
        Bp.u[2] = pk_tr(tb[4], tb[5]); Bp.u[3] = pk_tr(tb[6], tb[7]);
        const float4v D0 = __builtin_amdgcn_mfma_f32_16x16x32_bf16(e0.v, Bp.v, zerov, 0, 0, 0);
        const float4v D1 = __builtin_amdgcn_mfma_f32_16x16x32_bf16(e1.v, Bp.v, zerov, 0, 0, 0);
#pragma unroll
        for (int i = 0; i < 4; ++i) {
          a[i] = mv ? D0[i] : a[i];
          a[4 + i] = mv ? D1[i] : a[4 + i];
        }
      }
      if (j == CH - 1) {  // renorm once per chunk (8 steps, growth < 2^110)
        float mx = fmaxf(fmaxf(fmaxf(a[0], a[1]), fmaxf(a[2], a[3])),
                         fmaxf(fmaxf(a[4], a[5]), fmaxf(a[6], a[7])));
        mx = fmaxf(mx, __shfl_xor(mx, 16, 64));
        mx = fmaxf(mx, __shfl_xor(mx, 32, 64));
        const int ex = (int)((__float_as_uint(mx) >> 23) & 0xFFu) - 127;
        const float scl = __uint_as_float((unsigned)(127 - ex) << 23);  // exact 2^-ex
#pragma unroll
        for (int i = 0; i < 8; ++i) a[i] *= scl;
        c2 += (float)ex;
      }
      if (FWD) {
        Bf.u[0] = pk_tr(a[0], a[1]); Bf.u[1] = pk_tr(a[2], a[3]);
        Bf.u[2] = pk_tr(a[4], a[5]); Bf.u[3] = pk_tr(a[6], a[7]);
      }
    }
    __syncthreads();  // chunk k consumed; producer's chunk k+1 landed
  }

  // ---- junction: out[b] = ln2 * (c2f + c2b + log2(dot(u, alpha)))
  if (!FWD) {
    float4v lo = {a[0], a[1], a[2], a[3]}, hi = {a[4], a[5], a[6], a[7]};
    *(float4v*)(vbuf + lane * 8) = lo;
    *(float4v*)(vbuf + lane * 8 + 4) = hi;
    if (lane < 16) c2buf[lane] = c2;
  }
  __syncthreads();  // junction barrier
  if (FWD) {
    const float4v v0 = *(const float4v*)(vbuf + lane * 8);
    const float4v v1 = *(const float4v*)(vbuf + lane * 8 + 4);
    float dot = a[0] * v0[0] + a[1] * v0[1] + a[2] * v0[2] + a[3] * v0[3] +
                a[4] * v1[0] + a[5] * v1[1] + a[6] * v1[2] + a[7] * v1[3];
    dot += __shfl_xor(dot, 16, 64);
    dot += __shfl_xor(dot, 32, 64);
    if (lane < 16)
      out[b0 + lane] = LN2 * (c2 + c2buf[lane] + __builtin_amdgcn_logf(dot));
  }
}

extern "C" __global__ void __launch_bounds__(256, 1) crf_scan(
    const float* __restrict__ feats, const float* __restrict__ mask,
    const float* __restrict__ trans, float* __restrict__ out) {
  __shared__ float FF[2][2][FSLOT];  // [dir][buf][...] 64 KB
  __shared__ float MM[2][2][MSLOT];  // 2 KB
  __shared__ float vbuf[512];        // 2 KB
  __shared__ float c2buf[16];
  const int wid = threadIdx.x >> 6;
  const int lane = threadIdx.x & 63;
  const int b0 = blockIdx.x * 16;  // 16 batches per block

  if (wid == 0)
    consume<true>(trans, out, &FF[0][0][0], &MM[0][0][0], vbuf, c2buf, b0, lane);
  else if (wid == 1)
    consume<false>(trans, out, &FF[1][0][0], &MM[1][0][0], vbuf, c2buf, b0, lane);
  else if (wid == 2)
    produce<true>(feats, mask, &FF[0][0][0], &MM[0][0][0], b0, lane);
  else
    produce<false>(feats, mask, &FF[1][0][0], &MM[1][0][0], b0, lane);
}

extern "C" void kernel_launch(void* const* d_in, const int* in_sizes, int n_in,
                              void* d_out, int out_size, void* d_ws, size_t ws_size,
                              hipStream_t stream) {
  const float* feats = (const float*)d_in[0];
  const float* mask  = (const float*)d_in[1];
  const float* trans = (const float*)d_in[2];
  float* out = (float*)d_out;
  hipLaunchKernelGGL(crf_scan, dim3(BATCH / 16), dim3(256), 0, stream,
                     feats, mask, trans, out);
}